// Round 11
// baseline (119.077 us; speedup 1.0000x reference)
//
#include <hip/hip_runtime.h>
#include <stdint.h>

#define N_SITES 100000
#define NPAD    100032   // N rounded up to multiple of 64 (k1 grid)
#define CIN 64
#define CMID 384
#define COUT 64
#define SHIFT 16

typedef int   v4i __attribute__((ext_vector_type(4)));
typedef unsigned int v4u __attribute__((ext_vector_type(4)));
typedef float v4f __attribute__((ext_vector_type(4)));

// ---------------------------------------------------------------------------
// pack_w (480 blocks = 122880 threads):
//  o <  24576          : w1p MFMA A-table  [t=24][l=64][b=16]
//  o3 = o-24576 < 24576: w3p MFMA A-table  [ks=6][t=4][l=64][b=16]
//  o4 = o-49152 < 73728: w2t block-diagonal depthwise A-table
//        [cg=24][kk=3][l=64][b=16]:
//        q=l>>4, tap=kk*4+q; val = (tap<9 && b==(l&15))
//                                  ? wdw[tap][cg*16 + b] : 0
//  plus q1/q3 int arrays, bs2 packed (b lo16 | s hi16), zero sentinel row.
// ---------------------------------------------------------------------------
__global__ __launch_bounds__(256) void pack_w(
    const float* __restrict__ w1, const float* __restrict__ w3,
    const float* __restrict__ b1, const float* __restrict__ s1,
    const float* __restrict__ b2, const float* __restrict__ s2,
    const float* __restrict__ b3, const float* __restrict__ s3,
    const float* __restrict__ wdw,
    int8_t* __restrict__ w1p, int8_t* __restrict__ w3p,
    int8_t* __restrict__ w2t,
    int* __restrict__ q1, int* __restrict__ q3, int* __restrict__ bs2,
    int8_t* __restrict__ x1s)
{
    int o = blockIdx.x * 256 + threadIdx.x;
    if (o < 24 * 64 * 16) {                       // w1p
        int t = o >> 10, l = (o >> 4) & 63, b = o & 15;
        int k = ((l >> 4) << 4) + b;
        int col = t * 16 + (l & 15);
        w1p[o] = (int8_t)__float2int_rn(w1[k * CMID + col]);
    }
    int o3 = o - 24 * 64 * 16;
    if (o3 >= 0 && o3 < 6 * 4 * 64 * 16) {        // w3p
        int ks = o3 >> 12, t = (o3 >> 10) & 3;
        int l = (o3 >> 4) & 63, b = o3 & 15;
        int k = ks * 64 + ((l >> 4) << 4) + b;
        int col = t * 16 + (l & 15);
        w3p[o3] = (int8_t)__float2int_rn(w3[k * COUT + col]);
    }
    int o4 = o - 48 * 64 * 16;
    if (o4 >= 0 && o4 < 24 * 3 * 64 * 16) {       // w2t
        int cg = o4 / 3072;
        int rem = o4 - cg * 3072;
        int kk = rem >> 10;
        int l  = (rem >> 4) & 63;
        int b  = o4 & 15;
        int q  = l >> 4;
        int tap = kk * 4 + q;
        int8_t val = 0;
        if (tap < 9 && b == (l & 15))
            val = (int8_t)__float2int_rn(wdw[tap * CMID + cg * 16 + b]);
        w2t[o4] = val;
    }
    if (o < CMID) {
        q1[o] = __float2int_rn(b1[o]);
        q1[CMID + o] = __float2int_rn(s1[o]);
        int bb = __float2int_rn(b2[o]);            // [-1024,1024] fits i16
        int ss = __float2int_rn(s2[o]);            // [1,64]
        bs2[o] = (bb & 0xFFFF) | (ss << 16);
        x1s[(size_t)N_SITES * CMID + o] = 0;       // zero sentinel row
    }
    if (o < COUT) {
        q3[o] = __float2int_rn(b3[o]);
        q3[COUT + o] = __float2int_rn(s3[o]);
    }
}

// ---------------------------------------------------------------------------
// K1: fused f32->i8 convert + 1x1 expand MFMA (r8-proven, unchanged).
// ---------------------------------------------------------------------------
__global__ __launch_bounds__(256) void k1_mfma(
    const float* __restrict__ feats, const int8_t* __restrict__ w1p,
    const int* __restrict__ q1, int8_t* __restrict__ x1s)
{
    __shared__ int8_t xt[64 * 400];                // 25.6 KB
    const int lane = threadIdx.x & 63;
    const int wave = threadIdx.x >> 6;
    const int sl = wave * 16 + (lane & 15);        // local site 0..63
    const int site = blockIdx.x * 64 + sl;
    const int rsite = min(site, N_SITES - 1);      // clamp loads
    const int cb = (lane >> 4) << 2;               // channel sub-offset 0,4,8,12

    v4i b;
    const float* fp = feats + (size_t)rsite * CIN + ((lane >> 4) << 4);
#pragma unroll
    for (int j = 0; j < 4; ++j) {
        const v4f f = *(const v4f*)(fp + 4 * j);
        uint32_t pk = (uint32_t)(__float2int_rn(f[0]) & 255)
                    | ((uint32_t)(__float2int_rn(f[1]) & 255) << 8)
                    | ((uint32_t)(__float2int_rn(f[2]) & 255) << 16)
                    | ((uint32_t)__float2int_rn(f[3]) << 24);
        b[j] = (int)pk;
    }

    const v4i* ap = (const v4i*)w1p + lane;
#pragma unroll
    for (int t = 0; t < 24; ++t) {
        v4i a = ap[t * 64];
        v4i acc = {0, 0, 0, 0};
        acc = __builtin_amdgcn_mfma_i32_16x16x64_i8(a, b, acc, 0, 0, 0);
        const int co = t * 16 + cb;                // 4 consecutive channels
        const v4i bi = *(const v4i*)(q1 + co);
        const v4i si = *(const v4i*)(q1 + CMID + co);
        uint32_t wrd = 0;
#pragma unroll
        for (int r = 0; r < 4; ++r) {
            int v = ((acc[r] + bi[r]) * si[r] + (1 << (SHIFT - 1))) >> SHIFT;
            v = max(0, min(127, v));
            wrd |= (uint32_t)v << (8 * r);
        }
        *(uint32_t*)(xt + sl * 400 + co) = wrd;
    }
    __syncthreads();

    int8_t* dst = x1s + (size_t)blockIdx.x * 64 * CMID;
#pragma unroll
    for (int it = 0; it < 6; ++it) {
        const int lin = it * 4096 + threadIdx.x * 16;   // byte index, < 24576
        const int r = lin / 384;
        const int c = lin - r * 384;
        const v4u val = *(const v4u*)(xt + r * 400 + c);
        if (blockIdx.x * 64 + r < N_SITES)              // protect sentinel/pad
            *(v4u*)(dst + lin) = val;
    }
}

// ---------------------------------------------------------------------------
// K2: depthwise as BLOCK-DIAGONAL MFMA. Wave = 16 sites. Per 16-ch chunk cg:
// 3 MFMA passes over K=(tap,c'); B = raw 16B gathers (zero unpack VALU),
// A = precomputed diag table. D: lane = 4 consecutive channels of one site ->
// 1 dword -> LDS (pitch 400, 2-way banks); wave fence; coalesced copy-out.
// 100000 = 3125 blocks * 2 waves * 16 sites exactly.
// ---------------------------------------------------------------------------
__global__ __launch_bounds__(128) void k2_mfma(
    const int8_t* __restrict__ x1s, const int* __restrict__ nbr,
    const int8_t* __restrict__ w2t, const int* __restrict__ bs2,
    int8_t* __restrict__ x2s)
{
    __shared__ int8_t xt[2][16 * 400];             // 12.8 KB
    const int lane = threadIdx.x & 63;
    const int wv = threadIdx.x >> 6;
    const int site0 = (blockIdx.x * 2 + wv) * 16;
    int8_t* xw = &xt[wv][0];
    const int q  = lane >> 4;
    const int sl = lane & 15;
    const int site = site0 + sl;

    // 3 neighbor row offsets (taps q, 4+q, clamp(8+q)); tap>=9 is killed by
    // zeros in the A table, the clamped gather just reads a valid row.
    int off[3];
#pragma unroll
    for (int kk = 0; kk < 3; ++kk) {
        int tap = kk * 4 + q;
        if (tap > 8) tap = 8;
        const int idx = nbr[site * 9 + tap];
        off[kk] = (idx << 8) + (idx << 7);         // idx*384
    }

#pragma unroll 1
    for (int cg = 0; cg < 24; ++cg) {
        const int c0 = cg << 4;
        v4i acc = {0, 0, 0, 0};
#pragma unroll
        for (int kk = 0; kk < 3; ++kk) {
            const v4i bfr = *(const v4i*)(x1s + off[kk] + c0);
            const v4i afr = *((const v4i*)w2t + (cg * 3 + kk) * 64 + lane);
            acc = __builtin_amdgcn_mfma_i32_16x16x64_i8(afr, bfr, acc, 0, 0, 0);
        }
        // quant: channels c0 + q*4 + r of site sl
        const v4i bsv = *(const v4i*)(bs2 + c0 + (q << 2));
        uint32_t wrd = 0;
#pragma unroll
        for (int r = 0; r < 4; ++r) {
            const int bb = (bsv[r] << 16) >> 16;   // sext low 16
            const int ss = bsv[r] >> 16;           // sext high 16
            int t = ((acc[r] + bb) * ss + (1 << (SHIFT - 1))) >> SHIFT;
            t = max(0, min(127, t));
            wrd |= (uint32_t)t << (8 * r);
        }
        *(uint32_t*)(xw + sl * 400 + c0 + (q << 2)) = wrd;
    }

    // wave-internal fence (r10-proven)
    __builtin_amdgcn_wave_barrier();
    asm volatile("s_waitcnt lgkmcnt(0)" ::: "memory");
    __builtin_amdgcn_wave_barrier();

    // coalesced copy-out: 16 sites x 384 B = 6 KB per wave, 96 B per lane
    int8_t* dst = x2s + (size_t)site0 * CMID;
#pragma unroll
    for (int it = 0; it < 6; ++it) {
        const int lin = it * 1024 + lane * 16;     // byte index, < 6144
        const int r = lin / 384;
        const int c = lin - r * 384;
        *(v4u*)(dst + lin) = *(const v4u*)(xw + r * 400 + c);
    }
}

// ---------------------------------------------------------------------------
// K3: 1x1 project MFMA (r8-proven, unchanged): padded LDS tile then one
// contiguous coalesced 16 KB block store.
// ---------------------------------------------------------------------------
__global__ __launch_bounds__(256) void k3_mfma(
    const int8_t* __restrict__ x2s, const int8_t* __restrict__ w3p,
    const int* __restrict__ q3, float* __restrict__ out)
{
    __shared__ float ot[64 * 68];                  // 17.4 KB
    const int lane = threadIdx.x & 63;
    const int wave = threadIdx.x >> 6;
    const int sl = wave * 16 + (lane & 15);
    const int site = blockIdx.x * 64 + sl;
    const int rsite = min(site, N_SITES - 1);
    const int cb = (lane >> 4) << 2;               // cout sub-offset 0,4,8,12
    const int8_t* xrow = x2s + (size_t)rsite * CMID + ((lane >> 4) << 4);

    v4i acc[4] = {{0,0,0,0},{0,0,0,0},{0,0,0,0},{0,0,0,0}};
#pragma unroll
    for (int ks = 0; ks < 6; ++ks) {
        const v4i bfr = *(const v4i*)(xrow + ks * 64);
#pragma unroll
        for (int t = 0; t < 4; ++t) {
            const v4i afr = *((const v4i*)w3p + (ks * 4 + t) * 64 + lane);
            acc[t] = __builtin_amdgcn_mfma_i32_16x16x64_i8(afr, bfr, acc[t], 0, 0, 0);
        }
    }
#pragma unroll
    for (int t = 0; t < 4; ++t) {
        const int co = t * 16 + cb;                // 4 consecutive couts
        const v4i bo = *(const v4i*)(q3 + co);
        const v4i so = *(const v4i*)(q3 + COUT + co);
        v4f o;
#pragma unroll
        for (int r = 0; r < 4; ++r) {
            int v = ((acc[t][r] + bo[r]) * so[r] + (1 << (SHIFT - 1))) >> SHIFT;
            v = max(-128, min(127, v));
            o[r] = (float)v;
        }
        *(v4f*)(&ot[sl * 68 + co]) = o;
    }
    __syncthreads();

    float* dst = out + (size_t)blockIdx.x * 64 * COUT;
#pragma unroll
    for (int it = 0; it < 4; ++it) {
        const int lin = it * 1024 + threadIdx.x * 4;    // float index, < 4096
        const int r = lin >> 6;
        const int c = lin & 63;
        const v4f val = *(const v4f*)(&ot[r * 68 + c]);
        if (blockIdx.x * 64 + r < N_SITES)
            *(v4f*)(dst + lin) = val;
    }
}

extern "C" void kernel_launch(void* const* d_in, const int* in_sizes, int n_in,
                              void* d_out, int out_size, void* d_ws, size_t ws_size,
                              hipStream_t stream) {
    const float* feats = (const float*)d_in[0];
    const float* w1    = (const float*)d_in[1];
    const float* b1    = (const float*)d_in[2];
    const float* s1    = (const float*)d_in[3];
    const float* wdw   = (const float*)d_in[4];
    const float* b2    = (const float*)d_in[5];
    const float* s2    = (const float*)d_in[6];
    const float* w3    = (const float*)d_in[7];
    const float* b3    = (const float*)d_in[8];
    const float* s3    = (const float*)d_in[9];
    const int*   nbr   = (const int*)d_in[10];
    float* out = (float*)d_out;

    int8_t* x1s  = (int8_t*)d_ws;                      // NPAD*384 (sentinel row inside)
    int8_t* x2s  = x1s + (size_t)(NPAD + 64) * CMID;   // NPAD*384
    int8_t* w1p  = x2s + (size_t)NPAD * CMID;          // 24576
    int8_t* w3p  = w1p + 24 * 64 * 16;                 // 24576
    int*    q1   = (int*)(w3p + 6 * 4 * 64 * 16);      // 2*384 ints
    int*    q3   = q1 + 2 * CMID;                      // 2*64 ints
    int8_t* w2t  = (int8_t*)(q3 + 2 * COUT);           // 73728 bytes
    int*    bs2  = (int*)(w2t + 24 * 3 * 64 * 16);     // 384 ints

    pack_w<<<480, 256, 0, stream>>>(w1, w3, b1, s1, b2, s2, b3, s3, wdw,
                                    w1p, w3p, w2t, q1, q3, bs2, x1s);
    k1_mfma<<<NPAD / 64, 256, 0, stream>>>(feats, w1p, q1, x1s);
    k2_mfma<<<N_SITES / 32, 128, 0, stream>>>(x1s, nbr, w2t, bs2, x2s);
    k3_mfma<<<NPAD / 64, 256, 0, stream>>>(x2s, w3p, q3, out);
}

// Round 12
// 108.802 us; speedup vs baseline: 1.0944x; 1.0944x over previous
//
#include <hip/hip_runtime.h>
#include <stdint.h>

#define N_SITES 100000
#define NPAD    100032   // N rounded up to multiple of 64 (k1 grid)
#define CIN 64
#define CMID 384
#define COUT 64
#define SHIFT 16

typedef int   v4i __attribute__((ext_vector_type(4)));
typedef unsigned int v4u __attribute__((ext_vector_type(4)));
typedef float v4f __attribute__((ext_vector_type(4)));

// ---------------------------------------------------------------------------
// pack_w (480 blocks): w1p/w3p MFMA A-tables, w2t block-diagonal depthwise
// A-table [cg=24][kk=3][l=64][b=16] (r11-proven), q1/q3 ints, bs2 packed,
// zero sentinel row.
// ---------------------------------------------------------------------------
__global__ __launch_bounds__(256) void pack_w(
    const float* __restrict__ w1, const float* __restrict__ w3,
    const float* __restrict__ b1, const float* __restrict__ s1,
    const float* __restrict__ b2, const float* __restrict__ s2,
    const float* __restrict__ b3, const float* __restrict__ s3,
    const float* __restrict__ wdw,
    int8_t* __restrict__ w1p, int8_t* __restrict__ w3p,
    int8_t* __restrict__ w2t,
    int* __restrict__ q1, int* __restrict__ q3, int* __restrict__ bs2,
    int8_t* __restrict__ x1s)
{
    int o = blockIdx.x * 256 + threadIdx.x;
    if (o < 24 * 64 * 16) {                       // w1p
        int t = o >> 10, l = (o >> 4) & 63, b = o & 15;
        int k = ((l >> 4) << 4) + b;
        int col = t * 16 + (l & 15);
        w1p[o] = (int8_t)__float2int_rn(w1[k * CMID + col]);
    }
    int o3 = o - 24 * 64 * 16;
    if (o3 >= 0 && o3 < 6 * 4 * 64 * 16) {        // w3p
        int ks = o3 >> 12, t = (o3 >> 10) & 3;
        int l = (o3 >> 4) & 63, b = o3 & 15;
        int k = ks * 64 + ((l >> 4) << 4) + b;
        int col = t * 16 + (l & 15);
        w3p[o3] = (int8_t)__float2int_rn(w3[k * COUT + col]);
    }
    int o4 = o - 48 * 64 * 16;
    if (o4 >= 0 && o4 < 24 * 3 * 64 * 16) {       // w2t
        int cg = o4 / 3072;
        int rem = o4 - cg * 3072;
        int kk = rem >> 10;
        int l  = (rem >> 4) & 63;
        int b  = o4 & 15;
        int q  = l >> 4;
        int tap = kk * 4 + q;
        int8_t val = 0;
        if (tap < 9 && b == (l & 15))
            val = (int8_t)__float2int_rn(wdw[tap * CMID + cg * 16 + b]);
        w2t[o4] = val;
    }
    if (o < CMID) {
        q1[o] = __float2int_rn(b1[o]);
        q1[CMID + o] = __float2int_rn(s1[o]);
        int bb = __float2int_rn(b2[o]);            // [-1024,1024] fits i16
        int ss = __float2int_rn(s2[o]);            // [1,64]
        bs2[o] = (bb & 0xFFFF) | (ss << 16);
        x1s[(size_t)N_SITES * CMID + o] = 0;       // zero sentinel row
    }
    if (o < COUT) {
        q3[o] = __float2int_rn(b3[o]);
        q3[COUT + o] = __float2int_rn(s3[o]);
    }
}

// ---------------------------------------------------------------------------
// K1: fused f32->i8 convert + 1x1 expand MFMA (r8-proven, unchanged).
// ---------------------------------------------------------------------------
__global__ __launch_bounds__(256) void k1_mfma(
    const float* __restrict__ feats, const int8_t* __restrict__ w1p,
    const int* __restrict__ q1, int8_t* __restrict__ x1s)
{
    __shared__ int8_t xt[64 * 400];                // 25.6 KB
    const int lane = threadIdx.x & 63;
    const int wave = threadIdx.x >> 6;
    const int sl = wave * 16 + (lane & 15);        // local site 0..63
    const int site = blockIdx.x * 64 + sl;
    const int rsite = min(site, N_SITES - 1);      // clamp loads
    const int cb = (lane >> 4) << 2;               // channel sub-offset 0,4,8,12

    v4i b;
    const float* fp = feats + (size_t)rsite * CIN + ((lane >> 4) << 4);
#pragma unroll
    for (int j = 0; j < 4; ++j) {
        const v4f f = *(const v4f*)(fp + 4 * j);
        uint32_t pk = (uint32_t)(__float2int_rn(f[0]) & 255)
                    | ((uint32_t)(__float2int_rn(f[1]) & 255) << 8)
                    | ((uint32_t)(__float2int_rn(f[2]) & 255) << 16)
                    | ((uint32_t)__float2int_rn(f[3]) << 24);
        b[j] = (int)pk;
    }

    const v4i* ap = (const v4i*)w1p + lane;
#pragma unroll
    for (int t = 0; t < 24; ++t) {
        v4i a = ap[t * 64];
        v4i acc = {0, 0, 0, 0};
        acc = __builtin_amdgcn_mfma_i32_16x16x64_i8(a, b, acc, 0, 0, 0);
        const int co = t * 16 + cb;                // 4 consecutive channels
        const v4i bi = *(const v4i*)(q1 + co);
        const v4i si = *(const v4i*)(q1 + CMID + co);
        uint32_t wrd = 0;
#pragma unroll
        for (int r = 0; r < 4; ++r) {
            int v = ((acc[r] + bi[r]) * si[r] + (1 << (SHIFT - 1))) >> SHIFT;
            v = max(0, min(127, v));
            wrd |= (uint32_t)v << (8 * r);
        }
        *(uint32_t*)(xt + sl * 400 + co) = wrd;
    }
    __syncthreads();

    int8_t* dst = x1s + (size_t)blockIdx.x * 64 * CMID;
#pragma unroll
    for (int it = 0; it < 6; ++it) {
        const int lin = it * 4096 + threadIdx.x * 16;   // byte index, < 24576
        const int r = lin / 384;
        const int c = lin - r * 384;
        const v4u val = *(const v4u*)(xt + r * 400 + c);
        if (blockIdx.x * 64 + r < N_SITES)              // protect sentinel/pad
            *(v4u*)(dst + lin) = val;
    }
}

// ---------------------------------------------------------------------------
// K2: depthwise as block-diagonal MFMA, PIPELINED. Wave = 16 sites.
// cg blocked by 8 with kk inside: per (cgb,kk) the lane loads 128 B
// CONSECUTIVE of its row (full-line use) + 8 A-fragments, then 8 independent
// MFMAs -> 24 loads/24 MFMAs in flight per block, latency amortized.
// Algebra identical to r11 (absmax-0 proven). 100000 = 3125 * 2 * 16.
// ---------------------------------------------------------------------------
__global__ __launch_bounds__(128) void k2_mfma(
    const int8_t* __restrict__ x1s, const int* __restrict__ nbr,
    const int8_t* __restrict__ w2t, const int* __restrict__ bs2,
    int8_t* __restrict__ x2s)
{
    __shared__ int8_t xt[2][16 * 400];             // 12.8 KB
    const int lane = threadIdx.x & 63;
    const int wv = threadIdx.x >> 6;
    const int site0 = (blockIdx.x * 2 + wv) * 16;
    int8_t* xw = &xt[wv][0];
    const int q  = lane >> 4;
    const int sl = lane & 15;
    const int site = site0 + sl;

    // 3 neighbor row offsets (taps q, 4+q, clamp(8+q)); tap>=9 is killed by
    // zeros in the A table, the clamped gather just reads a valid row.
    int off[3];
#pragma unroll
    for (int kk = 0; kk < 3; ++kk) {
        int tap = kk * 4 + q;
        if (tap > 8) tap = 8;
        const int idx = nbr[site * 9 + tap];
        off[kk] = (idx << 8) + (idx << 7);         // idx*384
    }

    const v4i* wt = (const v4i*)w2t;

#pragma unroll 1
    for (int cgb = 0; cgb < 3; ++cgb) {            // 8 cg's per block
        v4i acc[8];
#pragma unroll
        for (int j = 0; j < 8; ++j) acc[j] = (v4i){0, 0, 0, 0};

#pragma unroll
        for (int kk = 0; kk < 3; ++kk) {
            v4i bfr[8], afr[8];
#pragma unroll
            for (int j = 0; j < 8; ++j) {
                const int cg = cgb * 8 + j;
                bfr[j] = *(const v4i*)(x1s + off[kk] + (cg << 4));
                afr[j] = wt[(cg * 3 + kk) * 64 + lane];
            }
#pragma unroll
            for (int j = 0; j < 8; ++j)
                acc[j] = __builtin_amdgcn_mfma_i32_16x16x64_i8(afr[j], bfr[j],
                                                               acc[j], 0, 0, 0);
        }

#pragma unroll
        for (int j = 0; j < 8; ++j) {
            const int c0 = (cgb * 8 + j) << 4;
            const v4i bsv = *(const v4i*)(bs2 + c0 + (q << 2));
            uint32_t wrd = 0;
#pragma unroll
            for (int r = 0; r < 4; ++r) {
                const int bb = (bsv[r] << 16) >> 16;   // sext low 16
                const int ss = bsv[r] >> 16;           // sext high 16
                int t = ((acc[j][r] + bb) * ss + (1 << (SHIFT - 1))) >> SHIFT;
                t = max(0, min(127, t));
                wrd |= (uint32_t)t << (8 * r);
            }
            *(uint32_t*)(xw + sl * 400 + c0 + (q << 2)) = wrd;
        }
    }

    // wave-internal fence (r10/r11-proven)
    __builtin_amdgcn_wave_barrier();
    asm volatile("s_waitcnt lgkmcnt(0)" ::: "memory");
    __builtin_amdgcn_wave_barrier();

    // coalesced copy-out: 16 sites x 384 B = 6 KB per wave, 96 B per lane
    int8_t* dst = x2s + (size_t)site0 * CMID;
#pragma unroll
    for (int it = 0; it < 6; ++it) {
        const int lin = it * 1024 + lane * 16;     // byte index, < 6144
        const int r = lin / 384;
        const int c = lin - r * 384;
        *(v4u*)(dst + lin) = *(const v4u*)(xw + r * 400 + c);
    }
}

// ---------------------------------------------------------------------------
// K3: 1x1 project MFMA (r8-proven, unchanged).
// ---------------------------------------------------------------------------
__global__ __launch_bounds__(256) void k3_mfma(
    const int8_t* __restrict__ x2s, const int8_t* __restrict__ w3p,
    const int* __restrict__ q3, float* __restrict__ out)
{
    __shared__ float ot[64 * 68];                  // 17.4 KB
    const int lane = threadIdx.x & 63;
    const int wave = threadIdx.x >> 6;
    const int sl = wave * 16 + (lane & 15);
    const int site = blockIdx.x * 64 + sl;
    const int rsite = min(site, N_SITES - 1);
    const int cb = (lane >> 4) << 2;               // cout sub-offset 0,4,8,12
    const int8_t* xrow = x2s + (size_t)rsite * CMID + ((lane >> 4) << 4);

    v4i acc[4] = {{0,0,0,0},{0,0,0,0},{0,0,0,0},{0,0,0,0}};
#pragma unroll
    for (int ks = 0; ks < 6; ++ks) {
        const v4i bfr = *(const v4i*)(xrow + ks * 64);
#pragma unroll
        for (int t = 0; t < 4; ++t) {
            const v4i afr = *((const v4i*)w3p + (ks * 4 + t) * 64 + lane);
            acc[t] = __builtin_amdgcn_mfma_i32_16x16x64_i8(afr, bfr, acc[t], 0, 0, 0);
        }
    }
#pragma unroll
    for (int t = 0; t < 4; ++t) {
        const int co = t * 16 + cb;                // 4 consecutive couts
        const v4i bo = *(const v4i*)(q3 + co);
        const v4i so = *(const v4i*)(q3 + COUT + co);
        v4f o;
#pragma unroll
        for (int r = 0; r < 4; ++r) {
            int v = ((acc[t][r] + bo[r]) * so[r] + (1 << (SHIFT - 1))) >> SHIFT;
            v = max(-128, min(127, v));
            o[r] = (float)v;
        }
        *(v4f*)(&ot[sl * 68 + co]) = o;
    }
    __syncthreads();

    float* dst = out + (size_t)blockIdx.x * 64 * COUT;
#pragma unroll
    for (int it = 0; it < 4; ++it) {
        const int lin = it * 1024 + threadIdx.x * 4;    // float index, < 4096
        const int r = lin >> 6;
        const int c = lin & 63;
        const v4f val = *(const v4f*)(&ot[r * 68 + c]);
        if (blockIdx.x * 64 + r < N_SITES)
            *(v4f*)(dst + lin) = val;
    }
}

extern "C" void kernel_launch(void* const* d_in, const int* in_sizes, int n_in,
                              void* d_out, int out_size, void* d_ws, size_t ws_size,
                              hipStream_t stream) {
    const float* feats = (const float*)d_in[0];
    const float* w1    = (const float*)d_in[1];
    const float* b1    = (const float*)d_in[2];
    const float* s1    = (const float*)d_in[3];
    const float* wdw   = (const float*)d_in[4];
    const float* b2    = (const float*)d_in[5];
    const float* s2    = (const float*)d_in[6];
    const float* w3    = (const float*)d_in[7];
    const float* b3    = (const float*)d_in[8];
    const float* s3    = (const float*)d_in[9];
    const int*   nbr   = (const int*)d_in[10];
    float* out = (float*)d_out;

    int8_t* x1s  = (int8_t*)d_ws;                      // NPAD*384 (sentinel row inside)
    int8_t* x2s  = x1s + (size_t)(NPAD + 64) * CMID;   // NPAD*384
    int8_t* w1p  = x2s + (size_t)NPAD * CMID;          // 24576
    int8_t* w3p  = w1p + 24 * 64 * 16;                 // 24576
    int*    q1   = (int*)(w3p + 6 * 4 * 64 * 16);      // 2*384 ints
    int*    q3   = q1 + 2 * CMID;                      // 2*64 ints
    int8_t* w2t  = (int8_t*)(q3 + 2 * COUT);           // 73728 bytes
    int*    bs2  = (int*)(w2t + 24 * 3 * 64 * 16);     // 384 ints

    pack_w<<<480, 256, 0, stream>>>(w1, w3, b1, s1, b2, s2, b3, s3, wdw,
                                    w1p, w3p, w2t, q1, q3, bs2, x1s);
    k1_mfma<<<NPAD / 64, 256, 0, stream>>>(feats, w1p, q1, x1s);
    k2_mfma<<<N_SITES / 32, 128, 0, stream>>>(x1s, nbr, w2t, bs2, x2s);
    k3_mfma<<<NPAD / 64, 256, 0, stream>>>(x2s, w3p, q3, out);
}

// Round 13
// 101.366 us; speedup vs baseline: 1.1747x; 1.0734x over previous
//
#include <hip/hip_runtime.h>
#include <stdint.h>

#define N_SITES 100000
#define NPAD    100032   // N rounded up to multiple of 64 (k1 grid)
#define CIN 64
#define CMID 384
#define COUT 64
#define SHIFT 16

typedef int   v4i __attribute__((ext_vector_type(4)));
typedef unsigned int v4u __attribute__((ext_vector_type(4)));
typedef float v4f __attribute__((ext_vector_type(4)));

// ---------------------------------------------------------------------------
// pack_w (192 blocks): w1p/w3p MFMA A-tables (r8-proven), wdw32 int [9][384],
// q2b/q2s int arrays, q1/q3 ints, zero sentinel row.
// ---------------------------------------------------------------------------
__global__ __launch_bounds__(256) void pack_w(
    const float* __restrict__ w1, const float* __restrict__ w3,
    const float* __restrict__ b1, const float* __restrict__ s1,
    const float* __restrict__ b2, const float* __restrict__ s2,
    const float* __restrict__ b3, const float* __restrict__ s3,
    const float* __restrict__ wdw,
    int8_t* __restrict__ w1p, int8_t* __restrict__ w3p,
    int* __restrict__ q1, int* __restrict__ q3,
    int* __restrict__ wdw32, int* __restrict__ q2b, int* __restrict__ q2s,
    int8_t* __restrict__ x1s)
{
    int o = blockIdx.x * 256 + threadIdx.x;
    if (o < 24 * 64 * 16) {                       // w1p: [t=24][l=64][b=16]
        int t = o >> 10, l = (o >> 4) & 63, b = o & 15;
        int k = ((l >> 4) << 4) + b;
        int col = t * 16 + (l & 15);
        w1p[o] = (int8_t)__float2int_rn(w1[k * CMID + col]);
    }
    int o3 = o - 24 * 64 * 16;
    if (o3 >= 0 && o3 < 6 * 4 * 64 * 16) {        // w3p: [ks=6][t=4][l=64][b=16]
        int ks = o3 >> 12, t = (o3 >> 10) & 3;
        int l = (o3 >> 4) & 63, b = o3 & 15;
        int k = ks * 64 + ((l >> 4) << 4) + b;
        int col = t * 16 + (l & 15);
        w3p[o3] = (int8_t)__float2int_rn(w3[k * COUT + col]);
    }
    if (o < 9 * CMID)                              // wdw32: [k][c] int32
        wdw32[o] = __float2int_rn(wdw[o]);
    if (o < CMID) {
        q1[o] = __float2int_rn(b1[o]);
        q1[CMID + o] = __float2int_rn(s1[o]);
        q2b[o] = __float2int_rn(b2[o]);
        q2s[o] = __float2int_rn(s2[o]);
        x1s[(size_t)N_SITES * CMID + o] = 0;       // zero sentinel row
    }
    if (o < COUT) {
        q3[o] = __float2int_rn(b3[o]);
        q3[COUT + o] = __float2int_rn(s3[o]);
    }
}

// ---------------------------------------------------------------------------
// K1: fused f32->i8 convert + 1x1 expand MFMA (r8-proven, unchanged).
// ---------------------------------------------------------------------------
__global__ __launch_bounds__(256) void k1_mfma(
    const float* __restrict__ feats, const int8_t* __restrict__ w1p,
    const int* __restrict__ q1, int8_t* __restrict__ x1s)
{
    __shared__ int8_t xt[64 * 400];                // 25.6 KB
    const int lane = threadIdx.x & 63;
    const int wave = threadIdx.x >> 6;
    const int sl = wave * 16 + (lane & 15);        // local site 0..63
    const int site = blockIdx.x * 64 + sl;
    const int rsite = min(site, N_SITES - 1);      // clamp loads
    const int cb = (lane >> 4) << 2;               // channel sub-offset 0,4,8,12

    v4i b;
    const float* fp = feats + (size_t)rsite * CIN + ((lane >> 4) << 4);
#pragma unroll
    for (int j = 0; j < 4; ++j) {
        const v4f f = *(const v4f*)(fp + 4 * j);
        uint32_t pk = (uint32_t)(__float2int_rn(f[0]) & 255)
                    | ((uint32_t)(__float2int_rn(f[1]) & 255) << 8)
                    | ((uint32_t)(__float2int_rn(f[2]) & 255) << 16)
                    | ((uint32_t)__float2int_rn(f[3]) << 24);
        b[j] = (int)pk;
    }

    const v4i* ap = (const v4i*)w1p + lane;
#pragma unroll
    for (int t = 0; t < 24; ++t) {
        v4i a = ap[t * 64];
        v4i acc = {0, 0, 0, 0};
        acc = __builtin_amdgcn_mfma_i32_16x16x64_i8(a, b, acc, 0, 0, 0);
        const int co = t * 16 + cb;                // 4 consecutive channels
        const v4i bi = *(const v4i*)(q1 + co);
        const v4i si = *(const v4i*)(q1 + CMID + co);
        uint32_t wrd = 0;
#pragma unroll
        for (int r = 0; r < 4; ++r) {
            int v = ((acc[r] + bi[r]) * si[r] + (1 << (SHIFT - 1))) >> SHIFT;
            v = max(0, min(127, v));
            wrd |= (uint32_t)v << (8 * r);
        }
        *(uint32_t*)(xt + sl * 400 + co) = wrd;
    }
    __syncthreads();

    int8_t* dst = x1s + (size_t)blockIdx.x * 64 * CMID;
#pragma unroll
    for (int it = 0; it < 6; ++it) {
        const int lin = it * 4096 + threadIdx.x * 16;   // byte index, < 24576
        const int r = lin / 384;
        const int c = lin - r * 384;
        const v4u val = *(const v4u*)(xt + r * 400 + c);
        if (blockIdx.x * 64 + r < N_SITES)              // protect sentinel/pad
            *(v4u*)(dst + lin) = val;
    }
}

// ---------------------------------------------------------------------------
// K2: 3x3 depthwise, wave-uniform-chunk remap. Block = 64 sites x 4 chunk-
// waves (4 chunks share each 64-B x1 line on the same CU -> L1 reuse kept).
// Lane = one site's 16-ch chunk: 9 x 16B gathers (same volume as proven
// kernel); weights/bias/scale via SCALAR loads (readfirstlane'd chunk) ->
// 2 VALU/MAC (bfe + mad_i24 with SGPR operand), zero vector weight loads.
// Output staged in 4.3 KB LDS (2-way banks) -> 64B/site coalesced stores.
// ---------------------------------------------------------------------------
__global__ __launch_bounds__(256) void k2_dw(
    const int8_t* __restrict__ x1s, const int* __restrict__ nbr,
    const int* __restrict__ wdw32, const int* __restrict__ q2b,
    const int* __restrict__ q2s, int8_t* __restrict__ x2s)
{
    __shared__ int8_t xw[64][68];                  // 4.3 KB, pitch 68
    const int lane = threadIdx.x & 63;
    const int wv = threadIdx.x >> 6;
    const int sg = blockIdx.x / 6;                 // site group (64 sites)
    const int cq = blockIdx.x - sg * 6;            // chunk quad 0..5
    const int chunk = __builtin_amdgcn_readfirstlane(cq * 4 + wv);  // 0..23
    const int c0 = chunk << 4;
    const int site = sg * 64 + lane;
    const int rsite = min(site, N_SITES - 1);      // clamp loads

    const int* nb = nbr + rsite * 9;
    int idx[9];
#pragma unroll
    for (int k = 0; k < 9; ++k) idx[k] = nb[k];

    v4u V[9];
#pragma unroll
    for (int k = 0; k < 9; ++k)
        V[k] = *(const v4u*)(x1s + (size_t)idx[k] * CMID + c0);

    int acc[16];
#pragma unroll
    for (int j = 0; j < 16; ++j) acc[j] = 0;

#pragma unroll
    for (int k = 0; k < 9; ++k) {
        const int* wr = wdw32 + k * CMID + c0;     // wave-uniform -> s_load
#pragma unroll
        for (int j = 0; j < 4; ++j) {
#pragma unroll
            for (int b = 0; b < 4; ++b) {
                const int v = (int)((V[k][j] >> (8 * b)) & 0xff);  // [0,255]
                acc[j * 4 + b] = __mul24(v, wr[j * 4 + b]) + acc[j * 4 + b];
            }
        }
    }

    // quant: all constants wave-uniform (SGPR); |acc+b| < 2^18, s <= 64 ->
    // __mul24 exact (product < 2^24), same math as proven kernel.
    const int* bbp = q2b + c0;
    const int* ssp = q2s + c0;
#pragma unroll
    for (int j = 0; j < 4; ++j) {
        uint32_t wrd = 0;
#pragma unroll
        for (int b = 0; b < 4; ++b) {
            const int c = j * 4 + b;
            int t = (__mul24(acc[c] + bbp[c], ssp[c]) + (1 << (SHIFT - 1))) >> SHIFT;
            t = max(0, min(127, t));
            wrd |= (uint32_t)t << (8 * b);
        }
        *(uint32_t*)(&xw[lane][wv * 16 + j * 4]) = wrd;
    }
    __syncthreads();

    // coalesced copy-out: 64 sites x 64 B (this block's 4 chunks)
    const int sr = threadIdx.x >> 2;               // 0..63
    const int sq = threadIdx.x & 3;
    if (sg * 64 + sr < N_SITES) {
        const v4u val = *(const v4u*)(&xw[sr][sq * 16]);
        *(v4u*)(x2s + (size_t)(sg * 64 + sr) * CMID + cq * 64 + sq * 16) = val;
    }
}

// ---------------------------------------------------------------------------
// K3: 1x1 project MFMA (r8-proven, unchanged).
// ---------------------------------------------------------------------------
__global__ __launch_bounds__(256) void k3_mfma(
    const int8_t* __restrict__ x2s, const int8_t* __restrict__ w3p,
    const int* __restrict__ q3, float* __restrict__ out)
{
    __shared__ float ot[64 * 68];                  // 17.4 KB
    const int lane = threadIdx.x & 63;
    const int wave = threadIdx.x >> 6;
    const int sl = wave * 16 + (lane & 15);
    const int site = blockIdx.x * 64 + sl;
    const int rsite = min(site, N_SITES - 1);
    const int cb = (lane >> 4) << 2;               // cout sub-offset 0,4,8,12
    const int8_t* xrow = x2s + (size_t)rsite * CMID + ((lane >> 4) << 4);

    v4i acc[4] = {{0,0,0,0},{0,0,0,0},{0,0,0,0},{0,0,0,0}};
#pragma unroll
    for (int ks = 0; ks < 6; ++ks) {
        const v4i bfr = *(const v4i*)(xrow + ks * 64);
#pragma unroll
        for (int t = 0; t < 4; ++t) {
            const v4i afr = *((const v4i*)w3p + (ks * 4 + t) * 64 + lane);
            acc[t] = __builtin_amdgcn_mfma_i32_16x16x64_i8(afr, bfr, acc[t], 0, 0, 0);
        }
    }
#pragma unroll
    for (int t = 0; t < 4; ++t) {
        const int co = t * 16 + cb;                // 4 consecutive couts
        const v4i bo = *(const v4i*)(q3 + co);
        const v4i so = *(const v4i*)(q3 + COUT + co);
        v4f o;
#pragma unroll
        for (int r = 0; r < 4; ++r) {
            int v = ((acc[t][r] + bo[r]) * so[r] + (1 << (SHIFT - 1))) >> SHIFT;
            v = max(-128, min(127, v));
            o[r] = (float)v;
        }
        *(v4f*)(&ot[sl * 68 + co]) = o;
    }
    __syncthreads();

    float* dst = out + (size_t)blockIdx.x * 64 * COUT;
#pragma unroll
    for (int it = 0; it < 4; ++it) {
        const int lin = it * 1024 + threadIdx.x * 4;    // float index, < 4096
        const int r = lin >> 6;
        const int c = lin & 63;
        const v4f val = *(const v4f*)(&ot[r * 68 + c]);
        if (blockIdx.x * 64 + r < N_SITES)
            *(v4f*)(dst + lin) = val;
    }
}

extern "C" void kernel_launch(void* const* d_in, const int* in_sizes, int n_in,
                              void* d_out, int out_size, void* d_ws, size_t ws_size,
                              hipStream_t stream) {
    const float* feats = (const float*)d_in[0];
    const float* w1    = (const float*)d_in[1];
    const float* b1    = (const float*)d_in[2];
    const float* s1    = (const float*)d_in[3];
    const float* wdw   = (const float*)d_in[4];
    const float* b2    = (const float*)d_in[5];
    const float* s2    = (const float*)d_in[6];
    const float* w3    = (const float*)d_in[7];
    const float* b3    = (const float*)d_in[8];
    const float* s3    = (const float*)d_in[9];
    const int*   nbr   = (const int*)d_in[10];
    float* out = (float*)d_out;

    int8_t* x1s   = (int8_t*)d_ws;                     // NPAD*384 (sentinel row inside)
    int8_t* x2s   = x1s + (size_t)NPAD * CMID;         // NPAD*384
    int8_t* w1p   = x2s + (size_t)NPAD * CMID;         // 24576
    int8_t* w3p   = w1p + 24 * 64 * 16;                // 24576
    int*    q1    = (int*)(w3p + 6 * 4 * 64 * 16);     // 2*384 ints
    int*    q3    = q1 + 2 * CMID;                     // 2*64 ints
    int*    wdw32 = q3 + 2 * COUT;                     // 9*384 ints
    int*    q2b   = wdw32 + 9 * CMID;                  // 384 ints
    int*    q2s   = q2b + CMID;                        // 384 ints

    pack_w<<<192, 256, 0, stream>>>(w1, w3, b1, s1, b2, s2, b3, s3, wdw,
                                    w1p, w3p, q1, q3, wdw32, q2b, q2s, x1s);
    k1_mfma<<<NPAD / 64, 256, 0, stream>>>(feats, w1p, q1, x1s);
    // site groups = ceil(100000/64) = 1563; 6 chunk-quads each
    k2_dw<<<1563 * 6, 256, 0, stream>>>(x1s, nbr, wdw32, q2b, q2s, x2s);
    k3_mfma<<<NPAD / 64, 256, 0, stream>>>(x2s, w3p, q3, out);
}

// Round 14
// 89.507 us; speedup vs baseline: 1.3304x; 1.1325x over previous
//
#include <hip/hip_runtime.h>
#include <stdint.h>

#define N_SITES 100000
#define NPAD    100032   // N rounded up to multiple of 64 (k1 grid)
#define CIN 64
#define CMID 384
#define COUT 64
#define SHIFT 16

#define K2_GROUPS 1563          // ceil(100000/64) site groups
#define K2_BLOCKS (K2_GROUPS*6) // 9378

typedef int   v4i __attribute__((ext_vector_type(4)));
typedef unsigned int v4u __attribute__((ext_vector_type(4)));
typedef float v4f __attribute__((ext_vector_type(4)));

// ---------------------------------------------------------------------------
// pack_w (192 blocks): w1p/w3p MFMA A-tables (r8-proven), wdw32 int [9][384],
// q2b/q2s int arrays, q1/q3 ints, zero sentinel row.
// ---------------------------------------------------------------------------
__global__ __launch_bounds__(256) void pack_w(
    const float* __restrict__ w1, const float* __restrict__ w3,
    const float* __restrict__ b1, const float* __restrict__ s1,
    const float* __restrict__ b2, const float* __restrict__ s2,
    const float* __restrict__ b3, const float* __restrict__ s3,
    const float* __restrict__ wdw,
    int8_t* __restrict__ w1p, int8_t* __restrict__ w3p,
    int* __restrict__ q1, int* __restrict__ q3,
    int* __restrict__ wdw32, int* __restrict__ q2b, int* __restrict__ q2s,
    int8_t* __restrict__ x1s)
{
    int o = blockIdx.x * 256 + threadIdx.x;
    if (o < 24 * 64 * 16) {                       // w1p: [t=24][l=64][b=16]
        int t = o >> 10, l = (o >> 4) & 63, b = o & 15;
        int k = ((l >> 4) << 4) + b;
        int col = t * 16 + (l & 15);
        w1p[o] = (int8_t)__float2int_rn(w1[k * CMID + col]);
    }
    int o3 = o - 24 * 64 * 16;
    if (o3 >= 0 && o3 < 6 * 4 * 64 * 16) {        // w3p: [ks=6][t=4][l=64][b=16]
        int ks = o3 >> 12, t = (o3 >> 10) & 3;
        int l = (o3 >> 4) & 63, b = o3 & 15;
        int k = ks * 64 + ((l >> 4) << 4) + b;
        int col = t * 16 + (l & 15);
        w3p[o3] = (int8_t)__float2int_rn(w3[k * COUT + col]);
    }
    if (o < 9 * CMID)                              // wdw32: [k][c] int32
        wdw32[o] = __float2int_rn(wdw[o]);
    if (o < CMID) {
        q1[o] = __float2int_rn(b1[o]);
        q1[CMID + o] = __float2int_rn(s1[o]);
        q2b[o] = __float2int_rn(b2[o]);
        q2s[o] = __float2int_rn(s2[o]);
        x1s[(size_t)N_SITES * CMID + o] = 0;       // zero sentinel row
    }
    if (o < COUT) {
        q3[o] = __float2int_rn(b3[o]);
        q3[COUT + o] = __float2int_rn(s3[o]);
    }
}

// ---------------------------------------------------------------------------
// K1: fused f32->i8 convert + 1x1 expand MFMA (r8-proven, unchanged).
// ---------------------------------------------------------------------------
__global__ __launch_bounds__(256) void k1_mfma(
    const float* __restrict__ feats, const int8_t* __restrict__ w1p,
    const int* __restrict__ q1, int8_t* __restrict__ x1s)
{
    __shared__ int8_t xt[64 * 400];                // 25.6 KB
    const int lane = threadIdx.x & 63;
    const int wave = threadIdx.x >> 6;
    const int sl = wave * 16 + (lane & 15);        // local site 0..63
    const int site = blockIdx.x * 64 + sl;
    const int rsite = min(site, N_SITES - 1);      // clamp loads
    const int cb = (lane >> 4) << 2;               // channel sub-offset 0,4,8,12

    v4i b;
    const float* fp = feats + (size_t)rsite * CIN + ((lane >> 4) << 4);
#pragma unroll
    for (int j = 0; j < 4; ++j) {
        const v4f f = *(const v4f*)(fp + 4 * j);
        uint32_t pk = (uint32_t)(__float2int_rn(f[0]) & 255)
                    | ((uint32_t)(__float2int_rn(f[1]) & 255) << 8)
                    | ((uint32_t)(__float2int_rn(f[2]) & 255) << 16)
                    | ((uint32_t)__float2int_rn(f[3]) << 24);
        b[j] = (int)pk;
    }

    const v4i* ap = (const v4i*)w1p + lane;
#pragma unroll
    for (int t = 0; t < 24; ++t) {
        v4i a = ap[t * 64];
        v4i acc = {0, 0, 0, 0};
        acc = __builtin_amdgcn_mfma_i32_16x16x64_i8(a, b, acc, 0, 0, 0);
        const int co = t * 16 + cb;                // 4 consecutive channels
        const v4i bi = *(const v4i*)(q1 + co);
        const v4i si = *(const v4i*)(q1 + CMID + co);
        uint32_t wrd = 0;
#pragma unroll
        for (int r = 0; r < 4; ++r) {
            int v = ((acc[r] + bi[r]) * si[r] + (1 << (SHIFT - 1))) >> SHIFT;
            v = max(0, min(127, v));
            wrd |= (uint32_t)v << (8 * r);
        }
        *(uint32_t*)(xt + sl * 400 + co) = wrd;
    }
    __syncthreads();

    int8_t* dst = x1s + (size_t)blockIdx.x * 64 * CMID;
#pragma unroll
    for (int it = 0; it < 6; ++it) {
        const int lin = it * 4096 + threadIdx.x * 16;   // byte index, < 24576
        const int r = lin / 384;
        const int c = lin - r * 384;
        const v4u val = *(const v4u*)(xt + r * 400 + c);
        if (blockIdx.x * 64 + r < N_SITES)              // protect sentinel/pad
            *(v4u*)(dst + lin) = val;
    }
}

// ---------------------------------------------------------------------------
// K2: 3x3 depthwise, SGPR-weight remap (r13 body, absmax-0 proven) + XCD
// CO-LOCATION swizzle: under HW round-robin (xcd = blockIdx&7), remap so the
// 6 chunk-quad blocks of each 64-site group get consecutive work-ids on the
// SAME XCD -> each randomly-gathered x1 row is fetched into ONE L2 (fixes
// r13's 2x FETCH inflation). Bijective m204-style split.
// ---------------------------------------------------------------------------
__global__ __launch_bounds__(256) void k2_dw(
    const int8_t* __restrict__ x1s, const int* __restrict__ nbr,
    const int* __restrict__ wdw32, const int* __restrict__ q2b,
    const int* __restrict__ q2s, int8_t* __restrict__ x2s)
{
    __shared__ int8_t xw[64][68];                  // 4.3 KB, pitch 68
    // --- bijective XCD co-location remap (B = 9378 = 8*1172 + 2) ---
    const int xcd = blockIdx.x & 7;
    const int seq = blockIdx.x >> 3;
    const int qq = K2_BLOCKS >> 3;                 // 1172
    const int rr = K2_BLOCKS & 7;                  // 2
    const int wid = (xcd < rr ? xcd * (qq + 1) : rr * (qq + 1) + (xcd - rr) * qq)
                    + seq;
    const int sg = wid / 6;                        // site group (64 sites)
    const int cq = wid - sg * 6;                   // chunk quad 0..5

    const int lane = threadIdx.x & 63;
    const int wv = threadIdx.x >> 6;
    const int chunk = __builtin_amdgcn_readfirstlane(cq * 4 + wv);  // 0..23
    const int c0 = chunk << 4;
    const int site = sg * 64 + lane;
    const int rsite = min(site, N_SITES - 1);      // clamp loads

    const int* nb = nbr + rsite * 9;
    int idx[9];
#pragma unroll
    for (int k = 0; k < 9; ++k) idx[k] = nb[k];

    v4u V[9];
#pragma unroll
    for (int k = 0; k < 9; ++k)
        V[k] = *(const v4u*)(x1s + (size_t)idx[k] * CMID + c0);

    int acc[16];
#pragma unroll
    for (int j = 0; j < 16; ++j) acc[j] = 0;

#pragma unroll
    for (int k = 0; k < 9; ++k) {
        const int* wr = wdw32 + k * CMID + c0;     // wave-uniform -> s_load
#pragma unroll
        for (int j = 0; j < 4; ++j) {
#pragma unroll
            for (int b = 0; b < 4; ++b) {
                const int v = (int)((V[k][j] >> (8 * b)) & 0xff);  // [0,127]
                acc[j * 4 + b] = __mul24(v, wr[j * 4 + b]) + acc[j * 4 + b];
            }
        }
    }

    // quant: all constants wave-uniform (SGPR); |acc+b| < 2^18, s <= 64 ->
    // __mul24 exact, same math as proven kernel.
    const int* bbp = q2b + c0;
    const int* ssp = q2s + c0;
#pragma unroll
    for (int j = 0; j < 4; ++j) {
        uint32_t wrd = 0;
#pragma unroll
        for (int b = 0; b < 4; ++b) {
            const int c = j * 4 + b;
            int t = (__mul24(acc[c] + bbp[c], ssp[c]) + (1 << (SHIFT - 1))) >> SHIFT;
            t = max(0, min(127, t));
            wrd |= (uint32_t)t << (8 * b);
        }
        *(uint32_t*)(&xw[lane][wv * 16 + j * 4]) = wrd;
    }
    __syncthreads();

    // coalesced copy-out: 64 sites x 64 B (this block's 4 chunks)
    const int sr = threadIdx.x >> 2;               // 0..63
    const int sq = threadIdx.x & 3;
    if (sg * 64 + sr < N_SITES) {
        const v4u val = *(const v4u*)(&xw[sr][sq * 16]);
        *(v4u*)(x2s + (size_t)(sg * 64 + sr) * CMID + cq * 64 + sq * 16) = val;
    }
}

// ---------------------------------------------------------------------------
// K3: 1x1 project MFMA (r8-proven, unchanged).
// ---------------------------------------------------------------------------
__global__ __launch_bounds__(256) void k3_mfma(
    const int8_t* __restrict__ x2s, const int8_t* __restrict__ w3p,
    const int* __restrict__ q3, float* __restrict__ out)
{
    __shared__ float ot[64 * 68];                  // 17.4 KB
    const int lane = threadIdx.x & 63;
    const int wave = threadIdx.x >> 6;
    const int sl = wave * 16 + (lane & 15);
    const int site = blockIdx.x * 64 + sl;
    const int rsite = min(site, N_SITES - 1);
    const int cb = (lane >> 4) << 2;               // cout sub-offset 0,4,8,12
    const int8_t* xrow = x2s + (size_t)rsite * CMID + ((lane >> 4) << 4);

    v4i acc[4] = {{0,0,0,0},{0,0,0,0},{0,0,0,0},{0,0,0,0}};
#pragma unroll
    for (int ks = 0; ks < 6; ++ks) {
        const v4i bfr = *(const v4i*)(xrow + ks * 64);
#pragma unroll
        for (int t = 0; t < 4; ++t) {
            const v4i afr = *((const v4i*)w3p + (ks * 4 + t) * 64 + lane);
            acc[t] = __builtin_amdgcn_mfma_i32_16x16x64_i8(afr, bfr, acc[t], 0, 0, 0);
        }
    }
#pragma unroll
    for (int t = 0; t < 4; ++t) {
        const int co = t * 16 + cb;                // 4 consecutive couts
        const v4i bo = *(const v4i*)(q3 + co);
        const v4i so = *(const v4i*)(q3 + COUT + co);
        v4f o;
#pragma unroll
        for (int r = 0; r < 4; ++r) {
            int v = ((acc[t][r] + bo[r]) * so[r] + (1 << (SHIFT - 1))) >> SHIFT;
            v = max(-128, min(127, v));
            o[r] = (float)v;
        }
        *(v4f*)(&ot[sl * 68 + co]) = o;
    }
    __syncthreads();

    float* dst = out + (size_t)blockIdx.x * 64 * COUT;
#pragma unroll
    for (int it = 0; it < 4; ++it) {
        const int lin = it * 1024 + threadIdx.x * 4;    // float index, < 4096
        const int r = lin >> 6;
        const int c = lin & 63;
        const v4f val = *(const v4f*)(&ot[r * 68 + c]);
        if (blockIdx.x * 64 + r < N_SITES)
            *(v4f*)(dst + lin) = val;
    }
}

extern "C" void kernel_launch(void* const* d_in, const int* in_sizes, int n_in,
                              void* d_out, int out_size, void* d_ws, size_t ws_size,
                              hipStream_t stream) {
    const float* feats = (const float*)d_in[0];
    const float* w1    = (const float*)d_in[1];
    const float* b1    = (const float*)d_in[2];
    const float* s1    = (const float*)d_in[3];
    const float* wdw   = (const float*)d_in[4];
    const float* b2    = (const float*)d_in[5];
    const float* s2    = (const float*)d_in[6];
    const float* w3    = (const float*)d_in[7];
    const float* b3    = (const float*)d_in[8];
    const float* s3    = (const float*)d_in[9];
    const int*   nbr   = (const int*)d_in[10];
    float* out = (float*)d_out;

    int8_t* x1s   = (int8_t*)d_ws;                     // NPAD*384 (sentinel row inside)
    int8_t* x2s   = x1s + (size_t)NPAD * CMID;         // NPAD*384
    int8_t* w1p   = x2s + (size_t)NPAD * CMID;         // 24576
    int8_t* w3p   = w1p + 24 * 64 * 16;                // 24576
    int*    q1    = (int*)(w3p + 6 * 4 * 64 * 16);     // 2*384 ints
    int*    q3    = q1 + 2 * CMID;                     // 2*64 ints
    int*    wdw32 = q3 + 2 * COUT;                     // 9*384 ints
    int*    q2b   = wdw32 + 9 * CMID;                  // 384 ints
    int*    q2s   = q2b + CMID;                        // 384 ints

    pack_w<<<192, 256, 0, stream>>>(w1, w3, b1, s1, b2, s2, b3, s3, wdw,
                                    w1p, w3p, q1, q3, wdw32, q2b, q2s, x1s);
    k1_mfma<<<NPAD / 64, 256, 0, stream>>>(feats, w1p, q1, x1s);
    k2_dw<<<K2_BLOCKS, 256, 0, stream>>>(x1s, nbr, wdw32, q2b, q2s, x2s);
    k3_mfma<<<NPAD / 64, 256, 0, stream>>>(x2s, w3p, q3, out);
}

// Round 15
// 82.977 us; speedup vs baseline: 1.4351x; 1.0787x over previous
//
#include <hip/hip_runtime.h>
#include <stdint.h>

#define N_SITES 100000
#define CIN 64
#define CMID 384
#define COUT 64
#define SHIFT 16

typedef int   v4i __attribute__((ext_vector_type(4)));
typedef unsigned int v4u __attribute__((ext_vector_type(4)));
typedef float v4f __attribute__((ext_vector_type(4)));

// ---------------------------------------------------------------------------
// pack_w (192 blocks): w1p/w3p MFMA A-tables (r8-proven), wdw8 int8 [9][384],
// bs2 packed (b lo16 | s hi16), q1/q3 ints, zero sentinel row.
// ---------------------------------------------------------------------------
__global__ __launch_bounds__(256) void pack_w(
    const float* __restrict__ w1, const float* __restrict__ w3,
    const float* __restrict__ b1, const float* __restrict__ s1,
    const float* __restrict__ b2, const float* __restrict__ s2,
    const float* __restrict__ b3, const float* __restrict__ s3,
    const float* __restrict__ wdw,
    int8_t* __restrict__ w1p, int8_t* __restrict__ w3p,
    int* __restrict__ q1, int* __restrict__ q3,
    int8_t* __restrict__ wdw8, int* __restrict__ bs2,
    int8_t* __restrict__ x1s)
{
    int o = blockIdx.x * 256 + threadIdx.x;
    if (o < 24 * 64 * 16) {                       // w1p: [t=24][l=64][b=16]
        int t = o >> 10, l = (o >> 4) & 63, b = o & 15;
        int k = ((l >> 4) << 4) + b;
        int col = t * 16 + (l & 15);
        w1p[o] = (int8_t)__float2int_rn(w1[k * CMID + col]);
    }
    int o3 = o - 24 * 64 * 16;
    if (o3 >= 0 && o3 < 6 * 4 * 64 * 16) {        // w3p: [ks=6][t=4][l=64][b=16]
        int ks = o3 >> 12, t = (o3 >> 10) & 3;
        int l = (o3 >> 4) & 63, b = o3 & 15;
        int k = ks * 64 + ((l >> 4) << 4) + b;
        int col = t * 16 + (l & 15);
        w3p[o3] = (int8_t)__float2int_rn(w3[k * COUT + col]);
    }
    if (o < 9 * CMID)                              // wdw8: [k][c] int8
        wdw8[o] = (int8_t)__float2int_rn(wdw[o]);
    if (o < CMID) {
        q1[o] = __float2int_rn(b1[o]);
        q1[CMID + o] = __float2int_rn(s1[o]);
        int bb = __float2int_rn(b2[o]);            // [-1024,1024] fits i16
        int ss = __float2int_rn(s2[o]);            // [1,64]
        bs2[o] = (bb & 0xFFFF) | (ss << 16);
        x1s[(size_t)N_SITES * CMID + o] = 0;       // zero sentinel row
    }
    if (o < COUT) {
        q3[o] = __float2int_rn(b3[o]);
        q3[COUT + o] = __float2int_rn(s3[o]);
    }
}

// ---------------------------------------------------------------------------
// K1: fused f32->i8 convert + 1x1 expand MFMA (r8-proven structure), 32-site
// tile / 128 threads: grid 3125 (2x blocks -> turnover headroom), LDS 12.8 KB.
// ---------------------------------------------------------------------------
__global__ __launch_bounds__(128) void k1_mfma(
    const float* __restrict__ feats, const int8_t* __restrict__ w1p,
    const int* __restrict__ q1, int8_t* __restrict__ x1s)
{
    __shared__ int8_t xt[32 * 400];                // 12.8 KB
    const int lane = threadIdx.x & 63;
    const int wave = threadIdx.x >> 6;             // 0..1
    const int sl = wave * 16 + (lane & 15);        // local site 0..31
    const int site = blockIdx.x * 32 + sl;         // < 100000 exactly
    const int cb = (lane >> 4) << 2;               // channel sub-offset 0,4,8,12

    v4i b;
    const float* fp = feats + (size_t)site * CIN + ((lane >> 4) << 4);
#pragma unroll
    for (int j = 0; j < 4; ++j) {
        const v4f f = *(const v4f*)(fp + 4 * j);
        uint32_t pk = (uint32_t)(__float2int_rn(f[0]) & 255)
                    | ((uint32_t)(__float2int_rn(f[1]) & 255) << 8)
                    | ((uint32_t)(__float2int_rn(f[2]) & 255) << 16)
                    | ((uint32_t)__float2int_rn(f[3]) << 24);
        b[j] = (int)pk;
    }

    const v4i* ap = (const v4i*)w1p + lane;
#pragma unroll
    for (int t = 0; t < 24; ++t) {
        v4i a = ap[t * 64];
        v4i acc = {0, 0, 0, 0};
        acc = __builtin_amdgcn_mfma_i32_16x16x64_i8(a, b, acc, 0, 0, 0);
        const int co = t * 16 + cb;                // 4 consecutive channels
        const v4i bi = *(const v4i*)(q1 + co);
        const v4i si = *(const v4i*)(q1 + CMID + co);
        uint32_t wrd = 0;
#pragma unroll
        for (int r = 0; r < 4; ++r) {
            int v = ((acc[r] + bi[r]) * si[r] + (1 << (SHIFT - 1))) >> SHIFT;
            v = max(0, min(127, v));
            wrd |= (uint32_t)v << (8 * r);
        }
        *(uint32_t*)(xt + sl * 400 + co) = wrd;
    }
    __syncthreads();

    // contiguous coalesced copy-out: 32 rows x 384 B = 12 KB
    int8_t* dst = x1s + (size_t)blockIdx.x * 32 * CMID;
#pragma unroll
    for (int it = 0; it < 6; ++it) {
        const int lin = it * 2048 + threadIdx.x * 16;   // byte index, < 12288
        const int r = lin / 384;
        const int c = lin - r * 384;
        *(v4u*)(dst + lin) = *(const v4u*)(xt + r * 400 + c);
    }
}

// ---------------------------------------------------------------------------
// K2: 3x3 depthwise — EXACT r6 text (proven 43 us, best of 7 structures).
// thread = 16 channels of one site; tap-major MAC loop overlaps in-flight
// gathers; packed int8 weights (16 B/tap); ~3 rows/wave address locality.
// ---------------------------------------------------------------------------
__global__ __launch_bounds__(256) void k2_dw(
    const int8_t* __restrict__ x1s, const int* __restrict__ nbr,
    const int8_t* __restrict__ wdw8, const int* __restrict__ bs2,
    int8_t* __restrict__ x2s)
{
    const int g = blockIdx.x * 256 + threadIdx.x;
    const int site = g / 24;
    const int c0 = (g - site * 24) << 4;           // channel base, 0..368

    const int* nb = &nbr[site * 9];
    int idx[9];
#pragma unroll
    for (int k = 0; k < 9; ++k) idx[k] = nb[k];

    v4u V[9];
#pragma unroll
    for (int k = 0; k < 9; ++k) {
        const int off = (idx[k] << 8) + (idx[k] << 7) + c0;   // idx*384 + c0
        V[k] = *(const v4u*)(x1s + off);
    }

    int acc[16];
#pragma unroll
    for (int j = 0; j < 16; ++j) acc[j] = 0;

#pragma unroll
    for (int k = 0; k < 9; ++k) {
        const v4u W = *(const v4u*)(wdw8 + k * CMID + c0);
#pragma unroll
        for (int j = 0; j < 4; ++j) {
#pragma unroll
            for (int b = 0; b < 4; ++b) {
                const int v = (int)(uint8_t)(V[k][j] >> (8 * b));  // [0,127]
                const int w = (int)(int8_t)(W[j] >> (8 * b));      // [-128,127]
                acc[j * 4 + b] += v * w;           // v_mad_i32_i24
            }
        }
    }

    const v4i BS0 = *(const v4i*)(bs2 + c0);
    const v4i BS1 = *(const v4i*)(bs2 + c0 + 4);
    const v4i BS2 = *(const v4i*)(bs2 + c0 + 8);
    const v4i BS3 = *(const v4i*)(bs2 + c0 + 12);
    const v4i BS[4] = {BS0, BS1, BS2, BS3};

    v4u outw;
#pragma unroll
    for (int j = 0; j < 4; ++j) {
        uint32_t wrd = 0;
#pragma unroll
        for (int b = 0; b < 4; ++b) {
            const int bsv = BS[j][b];
            const int bb = (bsv << 16) >> 16;      // sext low 16
            const int ss = bsv >> 16;              // sext high 16
            int t = ((acc[j * 4 + b] + bb) * ss + (1 << (SHIFT - 1))) >> SHIFT;
            t = max(0, min(127, t));
            wrd |= (uint32_t)t << (8 * b);
        }
        outw[j] = wrd;
    }
    *(v4u*)(x2s + (site << 8) + (site << 7) + c0) = outw;
}

// ---------------------------------------------------------------------------
// K3: 1x1 project MFMA (r8-proven structure), 32-site tile / 128 threads:
// grid 3125, LDS 8.7 KB, contiguous coalesced 8 KB block store.
// ---------------------------------------------------------------------------
__global__ __launch_bounds__(128) void k3_mfma(
    const int8_t* __restrict__ x2s, const int8_t* __restrict__ w3p,
    const int* __restrict__ q3, float* __restrict__ out)
{
    __shared__ float ot[32 * 68];                  // 8.7 KB
    const int lane = threadIdx.x & 63;
    const int wave = threadIdx.x >> 6;             // 0..1
    const int sl = wave * 16 + (lane & 15);        // local site 0..31
    const int site = blockIdx.x * 32 + sl;         // < 100000 exactly
    const int cb = (lane >> 4) << 2;               // cout sub-offset 0,4,8,12
    const int8_t* xrow = x2s + (size_t)site * CMID + ((lane >> 4) << 4);

    v4i acc[4] = {{0,0,0,0},{0,0,0,0},{0,0,0,0},{0,0,0,0}};
#pragma unroll
    for (int ks = 0; ks < 6; ++ks) {
        const v4i bfr = *(const v4i*)(xrow + ks * 64);
#pragma unroll
        for (int t = 0; t < 4; ++t) {
            const v4i afr = *((const v4i*)w3p + (ks * 4 + t) * 64 + lane);
            acc[t] = __builtin_amdgcn_mfma_i32_16x16x64_i8(afr, bfr, acc[t], 0, 0, 0);
        }
    }
#pragma unroll
    for (int t = 0; t < 4; ++t) {
        const int co = t * 16 + cb;                // 4 consecutive couts
        const v4i bo = *(const v4i*)(q3 + co);
        const v4i so = *(const v4i*)(q3 + COUT + co);
        v4f o;
#pragma unroll
        for (int r = 0; r < 4; ++r) {
            int v = ((acc[t][r] + bo[r]) * so[r] + (1 << (SHIFT - 1))) >> SHIFT;
            v = max(-128, min(127, v));
            o[r] = (float)v;
        }
        *(v4f*)(&ot[sl * 68 + co]) = o;
    }
    __syncthreads();

    float* dst = out + (size_t)blockIdx.x * 32 * COUT;
#pragma unroll
    for (int it = 0; it < 4; ++it) {
        const int lin = it * 512 + threadIdx.x * 4;     // float index, < 2048
        const int r = lin >> 6;
        const int c = lin & 63;
        *(v4f*)(dst + lin) = *(const v4f*)(&ot[r * 68 + c]);
    }
}

extern "C" void kernel_launch(void* const* d_in, const int* in_sizes, int n_in,
                              void* d_out, int out_size, void* d_ws, size_t ws_size,
                              hipStream_t stream) {
    const float* feats = (const float*)d_in[0];
    const float* w1    = (const float*)d_in[1];
    const float* b1    = (const float*)d_in[2];
    const float* s1    = (const float*)d_in[3];
    const float* wdw   = (const float*)d_in[4];
    const float* b2    = (const float*)d_in[5];
    const float* s2    = (const float*)d_in[6];
    const float* w3    = (const float*)d_in[7];
    const float* b3    = (const float*)d_in[8];
    const float* s3    = (const float*)d_in[9];
    const int*   nbr   = (const int*)d_in[10];
    float* out = (float*)d_out;

    int8_t* x1s   = (int8_t*)d_ws;                     // N*384 + sentinel row
    int8_t* x2s   = x1s + (size_t)(N_SITES + 64) * CMID;  // N*384
    int8_t* w1p   = x2s + (size_t)N_SITES * CMID;      // 24576
    int8_t* w3p   = w1p + 24 * 64 * 16;                // 24576
    int*    q1    = (int*)(w3p + 6 * 4 * 64 * 16);     // 2*384 ints
    int*    q3    = q1 + 2 * CMID;                     // 2*64 ints
    int8_t* wdw8  = (int8_t*)(q3 + 2 * COUT);          // 9*384 bytes
    int*    bs2   = (int*)(wdw8 + 9 * CMID);           // 384 ints

    pack_w<<<192, 256, 0, stream>>>(w1, w3, b1, s1, b2, s2, b3, s3, wdw,
                                    w1p, w3p, q1, q3, wdw8, bs2, x1s);
    k1_mfma<<<N_SITES / 32, 128, 0, stream>>>(feats, w1p, q1, x1s);
    k2_dw<<<N_SITES * 24 / 256, 256, 0, stream>>>(x1s, nbr, wdw8, bs2, x2s);
    k3_mfma<<<N_SITES / 32, 128, 0, stream>>>(x2s, w3p, q3, out);
}